// Round 1
// baseline (3105.494 us; speedup 1.0000x reference)
//
#include <hip/hip_runtime.h>
#include <hip/hip_bf16.h>
#include <math.h>

// ChebyNet: 2-layer ChebConv (K=4), N=100000, E=1600000, F 32->16->10, log_softmax.
// Pipeline:
//   deg (atomic) -> dis = rsqrt -> norm[e]
//   L1: Tx1 = prop(x); Tx2 = 2*prop(Tx1) - x; Tx3 = 2*prop(Tx2) - Tx1
//       h = relu(b1 + sum_k Txk @ W1[k])
//   L2: same with h, W2, b2 -> log_softmax
// prop is implemented as: init out (0 or -Tx_{k-2}), then per-(edge,chunk4)
// gather float4 from v[src], atomicAdd scale*norm into out[dst].

#define BLK 256

__global__ void deg_kernel(const int* __restrict__ dst, float* __restrict__ deg, int E) {
    int e = blockIdx.x * blockDim.x + threadIdx.x;
    if (e < E) atomicAdd(&deg[dst[e]], 1.0f);
}

__global__ void dis_kernel(float* __restrict__ deg, int N) {
    int i = blockIdx.x * blockDim.x + threadIdx.x;
    if (i < N) {
        float d = deg[i];
        deg[i] = (d > 0.0f) ? rsqrtf(d) : 0.0f;
    }
}

__global__ void norm_kernel(const int* __restrict__ src, const int* __restrict__ dst,
                            const float* __restrict__ dis, float* __restrict__ nrm, int E) {
    int e = blockIdx.x * blockDim.x + threadIdx.x;
    if (e < E) nrm[e] = -dis[src[e]] * dis[dst[e]];
}

// out[i] = -in[i], vectorized; n4 = count/4
__global__ void neg_copy_kernel(const float* __restrict__ in, float* __restrict__ out, int n4) {
    int t = blockIdx.x * blockDim.x + threadIdx.x;
    if (t < n4) {
        float4 v = reinterpret_cast<const float4*>(in)[t];
        reinterpret_cast<float4*>(out)[t] = make_float4(-v.x, -v.y, -v.z, -v.w);
    }
}

// Sparse propagation: out[dst] += scale*norm[e] * v[src], 4 features per thread.
// F is 32 or 16 (power of two), C = F/4 chunks per edge; consecutive lanes take
// consecutive chunks of the same edge so the gather float4 loads are contiguous.
template <int F>
__global__ void prop_kernel(const int* __restrict__ src, const int* __restrict__ dst,
                            const float* __restrict__ nrm, const float* __restrict__ v,
                            float* __restrict__ out, float scale, int E) {
    constexpr int C = F / 4;
    int t = blockIdx.x * blockDim.x + threadIdx.x;
    int e = t / C;
    int c = t % C;
    if (e >= E) return;
    int s = src[e];
    int d = dst[e];
    float w = scale * nrm[e];
    float4 val = *reinterpret_cast<const float4*>(v + (size_t)s * F + c * 4);
    float* o = out + (size_t)d * F + c * 4;
    atomicAdd(o + 0, w * val.x);
    atomicAdd(o + 1, w * val.y);
    atomicAdd(o + 2, w * val.z);
    atomicAdd(o + 3, w * val.w);
}

// h[n,j] = relu(b1[j] + sum_k sum_i Txk[n,i] * W1[k,i,j]); F_IN=32, HID=16, K=4
__global__ void combine1_kernel(const float* __restrict__ x, const float* __restrict__ t1,
                                const float* __restrict__ t2, const float* __restrict__ t3,
                                const float* __restrict__ W1, const float* __restrict__ b1,
                                float* __restrict__ h, int N) {
    __shared__ float sW[4 * 32 * 16];  // 8 KB
    __shared__ float sb[16];
    for (int i = threadIdx.x; i < 4 * 32 * 16; i += blockDim.x) sW[i] = W1[i];
    if (threadIdx.x < 16) sb[threadIdx.x] = b1[threadIdx.x];
    __syncthreads();
    int n = blockIdx.x * blockDim.x + threadIdx.x;
    if (n >= N) return;
    float acc[16];
#pragma unroll
    for (int j = 0; j < 16; j++) acc[j] = sb[j];
    const float* rows[4] = {x + (size_t)n * 32, t1 + (size_t)n * 32,
                            t2 + (size_t)n * 32, t3 + (size_t)n * 32};
#pragma unroll
    for (int k = 0; k < 4; k++) {
        const float* row = rows[k];
        const float* Wk = sW + k * 512;
#pragma unroll
        for (int i = 0; i < 32; i++) {
            float xv = row[i];
#pragma unroll
            for (int j = 0; j < 16; j++) acc[j] += xv * Wk[i * 16 + j];
        }
    }
    float* ho = h + (size_t)n * 16;
#pragma unroll
    for (int j = 0; j < 16; j++) ho[j] = fmaxf(acc[j], 0.0f);
}

// o[n,c] = b2[c] + sum_k sum_i Sk[n,i]*W2[k,i,c]; then log_softmax over c. HID=16, C_OUT=10
__global__ void combine2_kernel(const float* __restrict__ h, const float* __restrict__ s1,
                                const float* __restrict__ s2, const float* __restrict__ s3,
                                const float* __restrict__ W2, const float* __restrict__ b2,
                                float* __restrict__ out, int N) {
    __shared__ float sW[4 * 16 * 10];
    __shared__ float sb[10];
    for (int i = threadIdx.x; i < 4 * 16 * 10; i += blockDim.x) sW[i] = W2[i];
    if (threadIdx.x < 10) sb[threadIdx.x] = b2[threadIdx.x];
    __syncthreads();
    int n = blockIdx.x * blockDim.x + threadIdx.x;
    if (n >= N) return;
    float acc[10];
#pragma unroll
    for (int c = 0; c < 10; c++) acc[c] = sb[c];
    const float* rows[4] = {h + (size_t)n * 16, s1 + (size_t)n * 16,
                            s2 + (size_t)n * 16, s3 + (size_t)n * 16};
#pragma unroll
    for (int k = 0; k < 4; k++) {
        const float* row = rows[k];
        const float* Wk = sW + k * 160;
#pragma unroll
        for (int i = 0; i < 16; i++) {
            float xv = row[i];
#pragma unroll
            for (int c = 0; c < 10; c++) acc[c] += xv * Wk[i * 10 + c];
        }
    }
    // log_softmax
    float m = acc[0];
#pragma unroll
    for (int c = 1; c < 10; c++) m = fmaxf(m, acc[c]);
    float sum = 0.0f;
#pragma unroll
    for (int c = 0; c < 10; c++) sum += expf(acc[c] - m);
    float lse = m + logf(sum);
    float* o = out + (size_t)n * 10;
#pragma unroll
    for (int c = 0; c < 10; c++) o[c] = acc[c] - lse;
}

extern "C" void kernel_launch(void* const* d_in, const int* in_sizes, int n_in,
                              void* d_out, int out_size, void* d_ws, size_t ws_size,
                              hipStream_t stream) {
    const float* x  = (const float*)d_in[0];
    const int*   ei = (const int*)d_in[1];
    const float* W1 = (const float*)d_in[2];
    const float* b1 = (const float*)d_in[3];
    const float* W2 = (const float*)d_in[4];
    const float* b2 = (const float*)d_in[5];
    float* out = (float*)d_out;

    const int N = in_sizes[0] / 32;   // 100000
    const int E = in_sizes[1] / 2;    // 1600000
    const int* src = ei;
    const int* dst = ei + E;

    float* ws  = (float*)d_ws;
    float* dis = ws;                       // N
    float* nrm = dis + N;                  // E
    float* txA = nrm + E;                  // 32N
    float* txB = txA + (size_t)32 * N;     // 32N
    float* txC = txB + (size_t)32 * N;     // 32N
    float* hb  = txC + (size_t)32 * N;     // 16N
    // layer-2 buffers alias dead Tx regions (dead after combine1)
    float* s1 = txA;                       // 16N
    float* s2 = txA + (size_t)16 * N;      // 16N
    float* s3 = txB;                       // 16N

    int gE  = (E + BLK - 1) / BLK;
    int gN  = (N + BLK - 1) / BLK;
    int gP32 = (E * 8 + BLK - 1) / BLK;
    int gP16 = (E * 4 + BLK - 1) / BLK;
    int g32N4 = (32 * N / 4 + BLK - 1) / BLK;
    int g16N4 = (16 * N / 4 + BLK - 1) / BLK;

    // normalization
    hipMemsetAsync(dis, 0, (size_t)N * sizeof(float), stream);
    deg_kernel<<<gE, BLK, 0, stream>>>(dst, dis, E);
    dis_kernel<<<gN, BLK, 0, stream>>>(dis, N);
    norm_kernel<<<gE, BLK, 0, stream>>>(src, dst, dis, nrm, E);

    // ---- layer 1 (F=32) ----
    hipMemsetAsync(txA, 0, (size_t)32 * N * sizeof(float), stream);
    prop_kernel<32><<<gP32, BLK, 0, stream>>>(src, dst, nrm, x, txA, 1.0f, E);    // Tx1
    neg_copy_kernel<<<g32N4, BLK, 0, stream>>>(x, txB, 32 * N / 4);               // -Tx0
    prop_kernel<32><<<gP32, BLK, 0, stream>>>(src, dst, nrm, txA, txB, 2.0f, E);  // Tx2
    neg_copy_kernel<<<g32N4, BLK, 0, stream>>>(txA, txC, 32 * N / 4);             // -Tx1
    prop_kernel<32><<<gP32, BLK, 0, stream>>>(src, dst, nrm, txB, txC, 2.0f, E);  // Tx3
    combine1_kernel<<<gN, BLK, 0, stream>>>(x, txA, txB, txC, W1, b1, hb, N);

    // ---- layer 2 (F=16) ----
    hipMemsetAsync(s1, 0, (size_t)16 * N * sizeof(float), stream);
    prop_kernel<16><<<gP16, BLK, 0, stream>>>(src, dst, nrm, hb, s1, 1.0f, E);    // S1
    neg_copy_kernel<<<g16N4, BLK, 0, stream>>>(hb, s2, 16 * N / 4);
    prop_kernel<16><<<gP16, BLK, 0, stream>>>(src, dst, nrm, s1, s2, 2.0f, E);    // S2
    neg_copy_kernel<<<g16N4, BLK, 0, stream>>>(s1, s3, 16 * N / 4);
    prop_kernel<16><<<gP16, BLK, 0, stream>>>(src, dst, nrm, s2, s3, 2.0f, E);    // S3
    combine2_kernel<<<gN, BLK, 0, stream>>>(hb, s1, s2, s3, W2, b2, out, N);
}

// Round 2
// 544.416 us; speedup vs baseline: 5.7043x; 5.7043x over previous
//
#include <hip/hip_runtime.h>
#include <hip/hip_bf16.h>
#include <math.h>

// ChebyNet: 2-layer ChebConv (K=4), N=100000, E=1600000, F 32->16->10, log_softmax.
//
// R2: atomic scatter (800 MB HBM write-through per prop, measured R1) replaced by
// CSR-by-dst + gather-side reduction. CSR built once per launch:
//   hist (int atomics) -> exclusive scan (3 kernels) -> scatter (src, norm) permuted.
// prop_csr: thread = (node, 4-feature chunk); walks edge bucket, register acc,
// single write. Cheby recurrence folded into epilogue: out = scale*acc - prev.

#define BLK 256

__global__ void hist_kernel(const int* __restrict__ dst, int* __restrict__ deg, int E) {
    int e = blockIdx.x * blockDim.x + threadIdx.x;
    if (e < E) atomicAdd(&deg[dst[e]], 1);
}

__global__ void dis_kernel(const int* __restrict__ deg, float* __restrict__ dis, int N) {
    int i = blockIdx.x * blockDim.x + threadIdx.x;
    if (i < N) {
        int d = deg[i];
        dis[i] = (d > 0) ? rsqrtf((float)d) : 0.0f;
    }
}

// per-block sums of deg -> bsum[block]
__global__ void block_sums_kernel(const int* __restrict__ deg, int* __restrict__ bsum, int N) {
    __shared__ int sh[BLK];
    int i = blockIdx.x * BLK + threadIdx.x;
    sh[threadIdx.x] = (i < N) ? deg[i] : 0;
    __syncthreads();
    for (int off = BLK / 2; off > 0; off >>= 1) {
        if (threadIdx.x < off) sh[threadIdx.x] += sh[threadIdx.x + off];
        __syncthreads();
    }
    if (threadIdx.x == 0) bsum[blockIdx.x] = sh[0];
}

// sequential exclusive scan of bsum (nb ~ 391, trivial); also rowptr[N] = E
__global__ void scan_partials_kernel(int* __restrict__ bsum, int nb,
                                     int* __restrict__ rowptr, int N, int E) {
    if (blockIdx.x == 0 && threadIdx.x == 0) {
        int run = 0;
        for (int i = 0; i < nb; i++) { int t = bsum[i]; bsum[i] = run; run += t; }
        rowptr[N] = E;
    }
}

// rowptr[i] = exclusive_scan(deg)[i] via in-block scan + bsum offset
__global__ void scan_final_kernel(const int* __restrict__ deg, const int* __restrict__ bsum,
                                  int* __restrict__ rowptr, int N) {
    __shared__ int sh[BLK];
    int i = blockIdx.x * BLK + threadIdx.x;
    int v = (i < N) ? deg[i] : 0;
    sh[threadIdx.x] = v;
    __syncthreads();
    for (int off = 1; off < BLK; off <<= 1) {
        int t = (threadIdx.x >= off) ? sh[threadIdx.x - off] : 0;
        __syncthreads();
        sh[threadIdx.x] += t;
        __syncthreads();
    }
    if (i < N) rowptr[i] = sh[threadIdx.x] - v + bsum[blockIdx.x];
}

// bucket edges by dst: perm_src[pos] = src, perm_nrm[pos] = -dis[src]*dis[dst]
__global__ void scatter_kernel(const int* __restrict__ src, const int* __restrict__ dst,
                               const float* __restrict__ dis, const int* __restrict__ rowptr,
                               int* __restrict__ fill, int* __restrict__ psrc,
                               float* __restrict__ pnrm, int E) {
    int e = blockIdx.x * blockDim.x + threadIdx.x;
    if (e >= E) return;
    int s = src[e];
    int d = dst[e];
    int pos = rowptr[d] + atomicAdd(&fill[d], 1);
    psrc[pos] = s;
    pnrm[pos] = -dis[s] * dis[d];
}

// out[n] = scale * sum_{e in bucket(n)} nrm[e]*v[src[e]]  (- prev[n] if HAVE_PREV)
// thread t: node n = t/C, chunk c = t%C (4 floats). Register accumulate, one write.
template <int F, bool HAVE_PREV>
__global__ void prop_csr_kernel(const int* __restrict__ rowptr, const int* __restrict__ psrc,
                                const float* __restrict__ pnrm, const float* __restrict__ v,
                                const float* __restrict__ prev, float* __restrict__ out,
                                float scale, int N) {
    constexpr int C = F / 4;
    int t = blockIdx.x * blockDim.x + threadIdx.x;
    int n = t / C;
    int c = t % C;
    if (n >= N) return;
    int beg = rowptr[n];
    int end = rowptr[n + 1];
    const float4* v4 = reinterpret_cast<const float4*>(v);
    float4 acc = make_float4(0.f, 0.f, 0.f, 0.f);
    int i = beg;
    // 2-wide manual unroll keeps 2 random gathers in flight
    for (; i + 1 < end; i += 2) {
        int s0 = psrc[i], s1 = psrc[i + 1];
        float w0 = pnrm[i], w1 = pnrm[i + 1];
        float4 a = v4[(size_t)s0 * C + c];
        float4 b = v4[(size_t)s1 * C + c];
        acc.x += w0 * a.x + w1 * b.x;
        acc.y += w0 * a.y + w1 * b.y;
        acc.z += w0 * a.z + w1 * b.z;
        acc.w += w0 * a.w + w1 * b.w;
    }
    if (i < end) {
        int s0 = psrc[i];
        float w0 = pnrm[i];
        float4 a = v4[(size_t)s0 * C + c];
        acc.x += w0 * a.x; acc.y += w0 * a.y; acc.z += w0 * a.z; acc.w += w0 * a.w;
    }
    float4 r;
    if (HAVE_PREV) {
        float4 p = reinterpret_cast<const float4*>(prev)[(size_t)n * C + c];
        r = make_float4(scale * acc.x - p.x, scale * acc.y - p.y,
                        scale * acc.z - p.z, scale * acc.w - p.w);
    } else {
        r = make_float4(scale * acc.x, scale * acc.y, scale * acc.z, scale * acc.w);
    }
    reinterpret_cast<float4*>(out)[(size_t)n * C + c] = r;
}

// h[n,j] = relu(b1[j] + sum_k sum_i Txk[n,i] * W1[k,i,j]); F_IN=32, HID=16, K=4
__global__ void combine1_kernel(const float* __restrict__ x, const float* __restrict__ t1,
                                const float* __restrict__ t2, const float* __restrict__ t3,
                                const float* __restrict__ W1, const float* __restrict__ b1,
                                float* __restrict__ h, int N) {
    __shared__ float sW[4 * 32 * 16];  // 8 KB
    __shared__ float sb[16];
    for (int i = threadIdx.x; i < 4 * 32 * 16; i += blockDim.x) sW[i] = W1[i];
    if (threadIdx.x < 16) sb[threadIdx.x] = b1[threadIdx.x];
    __syncthreads();
    int n = blockIdx.x * blockDim.x + threadIdx.x;
    if (n >= N) return;
    float acc[16];
#pragma unroll
    for (int j = 0; j < 16; j++) acc[j] = sb[j];
    const float* rows[4] = {x + (size_t)n * 32, t1 + (size_t)n * 32,
                            t2 + (size_t)n * 32, t3 + (size_t)n * 32};
#pragma unroll
    for (int k = 0; k < 4; k++) {
        const float* row = rows[k];
        const float* Wk = sW + k * 512;
#pragma unroll
        for (int i = 0; i < 32; i++) {
            float xv = row[i];
#pragma unroll
            for (int j = 0; j < 16; j++) acc[j] += xv * Wk[i * 16 + j];
        }
    }
    float* ho = h + (size_t)n * 16;
#pragma unroll
    for (int j = 0; j < 16; j++) ho[j] = fmaxf(acc[j], 0.0f);
}

// o[n,c] = b2[c] + sum_k sum_i Sk[n,i]*W2[k,i,c]; then log_softmax. HID=16, C_OUT=10
__global__ void combine2_kernel(const float* __restrict__ h, const float* __restrict__ s1,
                                const float* __restrict__ s2, const float* __restrict__ s3,
                                const float* __restrict__ W2, const float* __restrict__ b2,
                                float* __restrict__ out, int N) {
    __shared__ float sW[4 * 16 * 10];
    __shared__ float sb[10];
    for (int i = threadIdx.x; i < 4 * 16 * 10; i += blockDim.x) sW[i] = W2[i];
    if (threadIdx.x < 10) sb[threadIdx.x] = b2[threadIdx.x];
    __syncthreads();
    int n = blockIdx.x * blockDim.x + threadIdx.x;
    if (n >= N) return;
    float acc[10];
#pragma unroll
    for (int c = 0; c < 10; c++) acc[c] = sb[c];
    const float* rows[4] = {h + (size_t)n * 16, s1 + (size_t)n * 16,
                            s2 + (size_t)n * 16, s3 + (size_t)n * 16};
#pragma unroll
    for (int k = 0; k < 4; k++) {
        const float* row = rows[k];
        const float* Wk = sW + k * 160;
#pragma unroll
        for (int i = 0; i < 16; i++) {
            float xv = row[i];
#pragma unroll
            for (int c = 0; c < 10; c++) acc[c] += xv * Wk[i * 10 + c];
        }
    }
    float m = acc[0];
#pragma unroll
    for (int c = 1; c < 10; c++) m = fmaxf(m, acc[c]);
    float sum = 0.0f;
#pragma unroll
    for (int c = 0; c < 10; c++) sum += expf(acc[c] - m);
    float lse = m + logf(sum);
    float* o = out + (size_t)n * 10;
#pragma unroll
    for (int c = 0; c < 10; c++) o[c] = acc[c] - lse;
}

extern "C" void kernel_launch(void* const* d_in, const int* in_sizes, int n_in,
                              void* d_out, int out_size, void* d_ws, size_t ws_size,
                              hipStream_t stream) {
    const float* x  = (const float*)d_in[0];
    const int*   ei = (const int*)d_in[1];
    const float* W1 = (const float*)d_in[2];
    const float* b1 = (const float*)d_in[3];
    const float* W2 = (const float*)d_in[4];
    const float* b2 = (const float*)d_in[5];
    float* out = (float*)d_out;

    const int N = in_sizes[0] / 32;   // 100000
    const int E = in_sizes[1] / 2;    // 1600000
    const int* src = ei;
    const int* dst = ei + E;

    const int NB = (N + BLK - 1) / BLK;

    // workspace layout (all region sizes multiples of 4 elems -> 16B alignment)
    char* w = (char*)d_ws;
    int*   deg    = (int*)w;              w += (size_t)N * 4;
    int*   rowptr = (int*)w;              w += (size_t)(N + 4) * 4;
    int*   fill   = (int*)w;              w += (size_t)N * 4;
    int*   bsum   = (int*)w;              w += 1024 * 4;
    float* dis    = (float*)w;            w += (size_t)N * 4;
    int*   psrc   = (int*)w;              w += (size_t)E * 4;
    float* pnrm   = (float*)w;            w += (size_t)E * 4;
    float* txA    = (float*)w;            w += (size_t)32 * N * 4;
    float* txB    = (float*)w;            w += (size_t)32 * N * 4;
    float* txC    = (float*)w;            w += (size_t)32 * N * 4;
    float* hb     = (float*)w;            w += (size_t)16 * N * 4;
    // layer-2 buffers alias dead Tx regions
    float* s1 = txA;
    float* s2 = txA + (size_t)16 * N;
    float* s3 = txB;

    int gE = (E + BLK - 1) / BLK;
    int gN = NB;
    int gP32 = (N * 8 + BLK - 1) / BLK;
    int gP16 = (N * 4 + BLK - 1) / BLK;

    // ---- CSR build ----
    hipMemsetAsync(deg, 0, (size_t)N * sizeof(int), stream);
    hipMemsetAsync(fill, 0, (size_t)N * sizeof(int), stream);
    hist_kernel<<<gE, BLK, 0, stream>>>(dst, deg, E);
    dis_kernel<<<gN, BLK, 0, stream>>>(deg, dis, N);
    block_sums_kernel<<<NB, BLK, 0, stream>>>(deg, bsum, N);
    scan_partials_kernel<<<1, 64, 0, stream>>>(bsum, NB, rowptr, N, E);
    scan_final_kernel<<<NB, BLK, 0, stream>>>(deg, bsum, rowptr, N);
    scatter_kernel<<<gE, BLK, 0, stream>>>(src, dst, dis, rowptr, fill, psrc, pnrm, E);

    // ---- layer 1 (F=32) ----
    prop_csr_kernel<32, false><<<gP32, BLK, 0, stream>>>(rowptr, psrc, pnrm, x,   nullptr, txA, 1.0f, N); // Tx1
    prop_csr_kernel<32, true ><<<gP32, BLK, 0, stream>>>(rowptr, psrc, pnrm, txA, x,       txB, 2.0f, N); // Tx2
    prop_csr_kernel<32, true ><<<gP32, BLK, 0, stream>>>(rowptr, psrc, pnrm, txB, txA,     txC, 2.0f, N); // Tx3
    combine1_kernel<<<gN, BLK, 0, stream>>>(x, txA, txB, txC, W1, b1, hb, N);

    // ---- layer 2 (F=16) ----
    prop_csr_kernel<16, false><<<gP16, BLK, 0, stream>>>(rowptr, psrc, pnrm, hb, nullptr, s1, 1.0f, N);   // S1
    prop_csr_kernel<16, true ><<<gP16, BLK, 0, stream>>>(rowptr, psrc, pnrm, s1, hb,      s2, 2.0f, N);   // S2
    prop_csr_kernel<16, true ><<<gP16, BLK, 0, stream>>>(rowptr, psrc, pnrm, s2, s1,      s3, 2.0f, N);   // S3
    combine2_kernel<<<gN, BLK, 0, stream>>>(hb, s1, s2, s3, W2, b2, out, N);
}

// Round 3
// 479.741 us; speedup vs baseline: 6.4733x; 1.1348x over previous
//
#include <hip/hip_runtime.h>
#include <hip/hip_bf16.h>
#include <math.h>

// ChebyNet: 2-layer ChebConv (K=4), N=100000, E=1600000, F 32->16->10, log_softmax.
//
// R3: scatter writes packed int2{src, bits(norm)} (one 8B store/edge -> one line
// touch, vs two 4B stores to two lines measured at 155MB WRITE_SIZE in R2).
// prop reads packed records (one load) with 4-wide gather unroll. Partials scan
// parallelized (was a serial 391-iter single-thread loop).

#define BLK 256

__global__ void hist_kernel(const int* __restrict__ dst, int* __restrict__ deg, int E) {
    int t = blockIdx.x * blockDim.x + threadIdx.x;
    int i = t * 4;
    if (i + 3 < E) {
        int4 d = *reinterpret_cast<const int4*>(dst + i);
        atomicAdd(&deg[d.x], 1);
        atomicAdd(&deg[d.y], 1);
        atomicAdd(&deg[d.z], 1);
        atomicAdd(&deg[d.w], 1);
    } else {
        for (; i < E; i++) atomicAdd(&deg[dst[i]], 1);
    }
}

__global__ void dis_kernel(const int* __restrict__ deg, float* __restrict__ dis, int N) {
    int i = blockIdx.x * blockDim.x + threadIdx.x;
    if (i < N) {
        int d = deg[i];
        dis[i] = (d > 0) ? rsqrtf((float)d) : 0.0f;
    }
}

// per-block sums of deg -> bsum[block]
__global__ void block_sums_kernel(const int* __restrict__ deg, int* __restrict__ bsum, int N) {
    __shared__ int sh[BLK];
    int i = blockIdx.x * BLK + threadIdx.x;
    sh[threadIdx.x] = (i < N) ? deg[i] : 0;
    __syncthreads();
    for (int off = BLK / 2; off > 0; off >>= 1) {
        if (threadIdx.x < off) sh[threadIdx.x] += sh[threadIdx.x + off];
        __syncthreads();
    }
    if (threadIdx.x == 0) bsum[blockIdx.x] = sh[0];
}

// exclusive scan of bsum in one 512-thread block (nb=391 here); rowptr[N]=E
__global__ void scan_partials_kernel(int* __restrict__ bsum, int nb,
                                     int* __restrict__ rowptr, int N, int E) {
    __shared__ int sh[512];
    int tid = threadIdx.x;
    if (nb <= 512) {
        int v = (tid < nb) ? bsum[tid] : 0;
        sh[tid] = v;
        __syncthreads();
        for (int off = 1; off < 512; off <<= 1) {
            int t = (tid >= off) ? sh[tid - off] : 0;
            __syncthreads();
            sh[tid] += t;
            __syncthreads();
        }
        if (tid < nb) bsum[tid] = sh[tid] - v;  // exclusive
    } else if (tid == 0) {
        int run = 0;
        for (int i = 0; i < nb; i++) { int t = bsum[i]; bsum[i] = run; run += t; }
    }
    if (tid == 0) rowptr[N] = E;
}

// rowptr[i] = exclusive_scan(deg)[i] via in-block scan + bsum offset
__global__ void scan_final_kernel(const int* __restrict__ deg, const int* __restrict__ bsum,
                                  int* __restrict__ rowptr, int N) {
    __shared__ int sh[BLK];
    int i = blockIdx.x * BLK + threadIdx.x;
    int v = (i < N) ? deg[i] : 0;
    sh[threadIdx.x] = v;
    __syncthreads();
    for (int off = 1; off < BLK; off <<= 1) {
        int t = (threadIdx.x >= off) ? sh[threadIdx.x - off] : 0;
        __syncthreads();
        sh[threadIdx.x] += t;
        __syncthreads();
    }
    if (i < N) rowptr[i] = sh[threadIdx.x] - v + bsum[blockIdx.x];
}

// bucket edges by dst: pedge[pos] = {src, float_bits(-dis[src]*dis[dst])}
__global__ void scatter_kernel(const int* __restrict__ src, const int* __restrict__ dst,
                               const float* __restrict__ dis, const int* __restrict__ rowptr,
                               int* __restrict__ fill, int2* __restrict__ pedge, int E) {
    int e = blockIdx.x * blockDim.x + threadIdx.x;
    if (e >= E) return;
    int s = src[e];
    int d = dst[e];
    int pos = rowptr[d] + atomicAdd(&fill[d], 1);
    int2 rec;
    rec.x = s;
    rec.y = __float_as_int(-dis[s] * dis[d]);
    pedge[pos] = rec;
}

// out[n] = scale * sum_{e in bucket(n)} nrm[e]*v[src[e]]  (- prev[n] if HAVE_PREV)
// thread t: node n = t/C, chunk c = t%C (4 floats). Register accumulate, one write.
// 4-wide unroll: 4 random float4 gathers in flight per iteration.
template <int F, bool HAVE_PREV>
__global__ void prop_csr_kernel(const int* __restrict__ rowptr, const int2* __restrict__ pedge,
                                const float* __restrict__ v, const float* __restrict__ prev,
                                float* __restrict__ out, float scale, int N) {
    constexpr int C = F / 4;
    int t = blockIdx.x * blockDim.x + threadIdx.x;
    int n = t / C;
    int c = t % C;
    if (n >= N) return;
    int beg = rowptr[n];
    int end = rowptr[n + 1];
    const float4* v4 = reinterpret_cast<const float4*>(v);
    float4 acc = make_float4(0.f, 0.f, 0.f, 0.f);
    int i = beg;
    for (; i + 3 < end; i += 4) {
        int2 r0 = pedge[i], r1 = pedge[i + 1], r2 = pedge[i + 2], r3 = pedge[i + 3];
        float4 a0 = v4[(size_t)r0.x * C + c];
        float4 a1 = v4[(size_t)r1.x * C + c];
        float4 a2 = v4[(size_t)r2.x * C + c];
        float4 a3 = v4[(size_t)r3.x * C + c];
        float w0 = __int_as_float(r0.y), w1 = __int_as_float(r1.y);
        float w2 = __int_as_float(r2.y), w3 = __int_as_float(r3.y);
        acc.x += w0 * a0.x + w1 * a1.x + w2 * a2.x + w3 * a3.x;
        acc.y += w0 * a0.y + w1 * a1.y + w2 * a2.y + w3 * a3.y;
        acc.z += w0 * a0.z + w1 * a1.z + w2 * a2.z + w3 * a3.z;
        acc.w += w0 * a0.w + w1 * a1.w + w2 * a2.w + w3 * a3.w;
    }
    for (; i < end; i++) {
        int2 r0 = pedge[i];
        float w0 = __int_as_float(r0.y);
        float4 a0 = v4[(size_t)r0.x * C + c];
        acc.x += w0 * a0.x; acc.y += w0 * a0.y; acc.z += w0 * a0.z; acc.w += w0 * a0.w;
    }
    float4 r;
    if (HAVE_PREV) {
        float4 p = reinterpret_cast<const float4*>(prev)[(size_t)n * C + c];
        r = make_float4(scale * acc.x - p.x, scale * acc.y - p.y,
                        scale * acc.z - p.z, scale * acc.w - p.w);
    } else {
        r = make_float4(scale * acc.x, scale * acc.y, scale * acc.z, scale * acc.w);
    }
    reinterpret_cast<float4*>(out)[(size_t)n * C + c] = r;
}

// h[n,j] = relu(b1[j] + sum_k sum_i Txk[n,i] * W1[k,i,j]); F_IN=32, HID=16, K=4
__global__ void combine1_kernel(const float* __restrict__ x, const float* __restrict__ t1,
                                const float* __restrict__ t2, const float* __restrict__ t3,
                                const float* __restrict__ W1, const float* __restrict__ b1,
                                float* __restrict__ h, int N) {
    __shared__ float sW[4 * 32 * 16];  // 8 KB
    __shared__ float sb[16];
    for (int i = threadIdx.x; i < 4 * 32 * 16; i += blockDim.x) sW[i] = W1[i];
    if (threadIdx.x < 16) sb[threadIdx.x] = b1[threadIdx.x];
    __syncthreads();
    int n = blockIdx.x * blockDim.x + threadIdx.x;
    if (n >= N) return;
    float acc[16];
#pragma unroll
    for (int j = 0; j < 16; j++) acc[j] = sb[j];
    const float* rows[4] = {x + (size_t)n * 32, t1 + (size_t)n * 32,
                            t2 + (size_t)n * 32, t3 + (size_t)n * 32};
#pragma unroll
    for (int k = 0; k < 4; k++) {
        const float* row = rows[k];
        const float* Wk = sW + k * 512;
#pragma unroll
        for (int i = 0; i < 32; i++) {
            float xv = row[i];
#pragma unroll
            for (int j = 0; j < 16; j++) acc[j] += xv * Wk[i * 16 + j];
        }
    }
    float* ho = h + (size_t)n * 16;
#pragma unroll
    for (int j = 0; j < 16; j++) ho[j] = fmaxf(acc[j], 0.0f);
}

// o[n,c] = b2[c] + sum_k sum_i Sk[n,i]*W2[k,i,c]; then log_softmax. HID=16, C_OUT=10
__global__ void combine2_kernel(const float* __restrict__ h, const float* __restrict__ s1,
                                const float* __restrict__ s2, const float* __restrict__ s3,
                                const float* __restrict__ W2, const float* __restrict__ b2,
                                float* __restrict__ out, int N) {
    __shared__ float sW[4 * 16 * 10];
    __shared__ float sb[10];
    for (int i = threadIdx.x; i < 4 * 16 * 10; i += blockDim.x) sW[i] = W2[i];
    if (threadIdx.x < 10) sb[threadIdx.x] = b2[threadIdx.x];
    __syncthreads();
    int n = blockIdx.x * blockDim.x + threadIdx.x;
    if (n >= N) return;
    float acc[10];
#pragma unroll
    for (int c = 0; c < 10; c++) acc[c] = sb[c];
    const float* rows[4] = {h + (size_t)n * 16, s1 + (size_t)n * 16,
                            s2 + (size_t)n * 16, s3 + (size_t)n * 16};
#pragma unroll
    for (int k = 0; k < 4; k++) {
        const float* row = rows[k];
        const float* Wk = sW + k * 160;
#pragma unroll
        for (int i = 0; i < 16; i++) {
            float xv = row[i];
#pragma unroll
            for (int c = 0; c < 10; c++) acc[c] += xv * Wk[i * 10 + c];
        }
    }
    float m = acc[0];
#pragma unroll
    for (int c = 1; c < 10; c++) m = fmaxf(m, acc[c]);
    float sum = 0.0f;
#pragma unroll
    for (int c = 0; c < 10; c++) sum += expf(acc[c] - m);
    float lse = m + logf(sum);
    float* o = out + (size_t)n * 10;
#pragma unroll
    for (int c = 0; c < 10; c++) o[c] = acc[c] - lse;
}

extern "C" void kernel_launch(void* const* d_in, const int* in_sizes, int n_in,
                              void* d_out, int out_size, void* d_ws, size_t ws_size,
                              hipStream_t stream) {
    const float* x  = (const float*)d_in[0];
    const int*   ei = (const int*)d_in[1];
    const float* W1 = (const float*)d_in[2];
    const float* b1 = (const float*)d_in[3];
    const float* W2 = (const float*)d_in[4];
    const float* b2 = (const float*)d_in[5];
    float* out = (float*)d_out;

    const int N = in_sizes[0] / 32;   // 100000
    const int E = in_sizes[1] / 2;    // 1600000
    const int* src = ei;
    const int* dst = ei + E;

    const int NB = (N + BLK - 1) / BLK;

    // workspace layout (all region sizes multiples of 4 elems -> 16B alignment)
    char* w = (char*)d_ws;
    int*   deg    = (int*)w;              w += (size_t)N * 4;
    int*   rowptr = (int*)w;              w += (size_t)(N + 4) * 4;
    int*   fill   = (int*)w;              w += (size_t)N * 4;
    int*   bsum   = (int*)w;              w += 1024 * 4;
    float* dis    = (float*)w;            w += (size_t)N * 4;
    int2*  pedge  = (int2*)w;             w += (size_t)E * 8;
    float* txA    = (float*)w;            w += (size_t)32 * N * 4;
    float* txB    = (float*)w;            w += (size_t)32 * N * 4;
    float* txC    = (float*)w;            w += (size_t)32 * N * 4;
    float* hb     = (float*)w;            w += (size_t)16 * N * 4;
    // layer-2 buffers alias dead Tx regions
    float* s1 = txA;
    float* s2 = txA + (size_t)16 * N;
    float* s3 = txB;

    int gE  = (E + BLK - 1) / BLK;
    int gE4 = (E / 4 + BLK - 1) / BLK;
    int gN  = NB;
    int gP32 = (N * 8 + BLK - 1) / BLK;
    int gP16 = (N * 4 + BLK - 1) / BLK;

    // ---- CSR build ----
    hipMemsetAsync(deg, 0, (size_t)N * sizeof(int), stream);
    hipMemsetAsync(fill, 0, (size_t)N * sizeof(int), stream);
    hist_kernel<<<gE4, BLK, 0, stream>>>(dst, deg, E);
    dis_kernel<<<gN, BLK, 0, stream>>>(deg, dis, N);
    block_sums_kernel<<<NB, BLK, 0, stream>>>(deg, bsum, N);
    scan_partials_kernel<<<1, 512, 0, stream>>>(bsum, NB, rowptr, N, E);
    scan_final_kernel<<<NB, BLK, 0, stream>>>(deg, bsum, rowptr, N);
    scatter_kernel<<<gE, BLK, 0, stream>>>(src, dst, dis, rowptr, fill, pedge, E);

    // ---- layer 1 (F=32) ----
    prop_csr_kernel<32, false><<<gP32, BLK, 0, stream>>>(rowptr, pedge, x,   nullptr, txA, 1.0f, N); // Tx1
    prop_csr_kernel<32, true ><<<gP32, BLK, 0, stream>>>(rowptr, pedge, txA, x,       txB, 2.0f, N); // Tx2
    prop_csr_kernel<32, true ><<<gP32, BLK, 0, stream>>>(rowptr, pedge, txB, txA,     txC, 2.0f, N); // Tx3
    combine1_kernel<<<gN, BLK, 0, stream>>>(x, txA, txB, txC, W1, b1, hb, N);

    // ---- layer 2 (F=16) ----
    prop_csr_kernel<16, false><<<gP16, BLK, 0, stream>>>(rowptr, pedge, hb, nullptr, s1, 1.0f, N);   // S1
    prop_csr_kernel<16, true ><<<gP16, BLK, 0, stream>>>(rowptr, pedge, s1, hb,      s2, 2.0f, N);   // S2
    prop_csr_kernel<16, true ><<<gP16, BLK, 0, stream>>>(rowptr, pedge, s2, s1,      s3, 2.0f, N);   // S3
    combine2_kernel<<<gN, BLK, 0, stream>>>(hb, s1, s2, s3, W2, b2, out, N);
}

// Round 4
// 457.431 us; speedup vs baseline: 6.7890x; 1.0488x over previous
//
#include <hip/hip_runtime.h>
#include <hip/hip_bf16.h>
#include <math.h>

// ChebyNet: 2-layer ChebConv (K=4), N=100000, E=1600000, F 32->16->10, log_softmax.
//
// R4: R3's scatter wrote 102 MB (= E x 64B: every random 8B store dirtied a full
// line; reuse distance >> L2). Replaced by two-phase bucketed build:
//   binned_scatter: LDS-group records by coarse bucket (dst>>9), flush coalesced
//   bucket_place:   per-bucket LDS rank + stage, flush coalesced
// Edge record is 4B packed (src<<9 | dst&511): norm dropped entirely --
// out[n] = -dis[n] * sum dis[src]*v[src], dst factor folded into prop epilogue,
// dis[src] gathered from the 400KB L2-resident table.

#define BLK 256
#define NBUCK_MAX 256   // buckets = ceil(N/512); requires N <= 131072 (src fits 17 bits too)
#define CHUNK 8192      // edges per binned_scatter block
#define PLACE_CAP 10240 // staging capacity in bucket_place (avg bucket = 8192)

__global__ void hist_kernel(const int* __restrict__ dst, int* __restrict__ deg, int E) {
    int t = blockIdx.x * blockDim.x + threadIdx.x;
    int i = t * 4;
    if (i + 3 < E) {
        int4 d = *reinterpret_cast<const int4*>(dst + i);
        atomicAdd(&deg[d.x], 1);
        atomicAdd(&deg[d.y], 1);
        atomicAdd(&deg[d.z], 1);
        atomicAdd(&deg[d.w], 1);
    } else {
        for (; i < E; i++) atomicAdd(&deg[dst[i]], 1);
    }
}

__global__ void dis_kernel(const int* __restrict__ deg, float* __restrict__ dis, int N) {
    int i = blockIdx.x * blockDim.x + threadIdx.x;
    if (i < N) {
        int d = deg[i];
        dis[i] = (d > 0) ? rsqrtf((float)d) : 0.0f;
    }
}

__global__ void block_sums_kernel(const int* __restrict__ deg, int* __restrict__ bsum, int N) {
    __shared__ int sh[BLK];
    int i = blockIdx.x * BLK + threadIdx.x;
    sh[threadIdx.x] = (i < N) ? deg[i] : 0;
    __syncthreads();
    for (int off = BLK / 2; off > 0; off >>= 1) {
        if (threadIdx.x < off) sh[threadIdx.x] += sh[threadIdx.x + off];
        __syncthreads();
    }
    if (threadIdx.x == 0) bsum[blockIdx.x] = sh[0];
}

__global__ void scan_partials_kernel(int* __restrict__ bsum, int nb,
                                     int* __restrict__ rowptr, int N, int E) {
    __shared__ int sh[512];
    int tid = threadIdx.x;
    if (nb <= 512) {
        int v = (tid < nb) ? bsum[tid] : 0;
        sh[tid] = v;
        __syncthreads();
        for (int off = 1; off < 512; off <<= 1) {
            int t = (tid >= off) ? sh[tid - off] : 0;
            __syncthreads();
            sh[tid] += t;
            __syncthreads();
        }
        if (tid < nb) bsum[tid] = sh[tid] - v;  // exclusive
    } else if (tid == 0) {
        int run = 0;
        for (int i = 0; i < nb; i++) { int t = bsum[i]; bsum[i] = run; run += t; }
    }
    if (tid == 0) rowptr[N] = E;
}

__global__ void scan_final_kernel(const int* __restrict__ deg, const int* __restrict__ bsum,
                                  int* __restrict__ rowptr, int N) {
    __shared__ int sh[BLK];
    int i = blockIdx.x * BLK + threadIdx.x;
    int v = (i < N) ? deg[i] : 0;
    sh[threadIdx.x] = v;
    __syncthreads();
    for (int off = 1; off < BLK; off <<= 1) {
        int t = (threadIdx.x >= off) ? sh[threadIdx.x - off] : 0;
        __syncthreads();
        sh[threadIdx.x] += t;
        __syncthreads();
    }
    if (i < N) rowptr[i] = sh[threadIdx.x] - v + bsum[blockIdx.x];
}

// Phase 1: group this block's CHUNK edges by bucket (dst>>9) in LDS, reserve
// global space per bucket, flush grouped runs coalesced into tmp.
// Record: (src << 9) | (dst & 511), 4 B.
__global__ void binned_scatter_kernel(const int* __restrict__ src, const int* __restrict__ dst,
                                      const int* __restrict__ rowptr, int* __restrict__ bfill,
                                      int* __restrict__ tmp, int E, int N, int nbuck) {
    __shared__ int cnt[NBUCK_MAX];
    __shared__ int lofs[NBUCK_MAX + 1];
    __shared__ int pos[NBUCK_MAX];
    __shared__ int gbase[NBUCK_MAX];
    __shared__ int stage[CHUNK];
    __shared__ unsigned char bkt[CHUNK];

    int tid = threadIdx.x;
    int e0 = blockIdx.x * CHUNK;
    int nE = min(CHUNK, E - e0);

    for (int b = tid; b < nbuck; b += BLK) { cnt[b] = 0; pos[b] = 0; }
    __syncthreads();

    // pass 1: histogram by bucket
    for (int i = tid; i < nE; i += BLK) {
        int d = dst[e0 + i];
        atomicAdd(&cnt[d >> 9], 1);
    }
    __syncthreads();

    // exclusive scan of cnt (256-wide Hillis-Steele) + global reservation
    {
        int v = (tid < nbuck) ? cnt[tid] : 0;
        lofs[tid] = v;
        __syncthreads();
        for (int off = 1; off < BLK; off <<= 1) {
            int t = (tid >= off) ? lofs[tid - off] : 0;
            __syncthreads();
            lofs[tid] += t;
            __syncthreads();
        }
        int incl = lofs[tid];
        __syncthreads();
        lofs[tid] = incl - v;  // exclusive
        if (tid == 0) lofs[nbuck] = nE;
        if (tid < nbuck && v > 0) {
            // bucket's CSR span starts at rowptr[512*b]
            gbase[tid] = rowptr[tid << 9] + atomicAdd(&bfill[tid], v);
        }
    }
    __syncthreads();

    // pass 2: place records grouped by bucket in LDS
    for (int i = tid; i < nE; i += BLK) {
        int s = src[e0 + i];
        int d = dst[e0 + i];
        int b = d >> 9;
        int slot = lofs[b] + atomicAdd(&pos[b], 1);
        stage[slot] = (s << 9) | (d & 511);
        bkt[slot] = (unsigned char)b;
    }
    __syncthreads();

    // flush: consecutive threads -> consecutive slots -> mostly-coalesced runs
    for (int i = tid; i < nE; i += BLK) {
        int b = bkt[i];
        tmp[gbase[b] + (i - lofs[b])] = stage[i];
    }
}

// Phase 2: one block per bucket. Rank each record within its node via LDS
// counters, stage final CSR order in LDS, flush coalesced. psrc[pos] = src.
__global__ void bucket_place_kernel(const int* __restrict__ rowptr, const int* __restrict__ tmp,
                                    int* __restrict__ psrc, int N, int nbuck) {
    __shared__ int locRow[513];
    __shared__ int fill[512];
    __shared__ int stage[PLACE_CAP];

    int b = blockIdx.x;
    int tid = threadIdx.x;
    int n0 = b << 9;
    int nn = min(512, N - n0);

    for (int i = tid; i <= nn; i += BLK) locRow[i] = rowptr[n0 + i];
    for (int i = tid; i < nn; i += BLK) fill[i] = 0;
    __syncthreads();

    int S = locRow[0];
    int cnt = locRow[nn] - S;

    if (cnt <= PLACE_CAP) {
        for (int i = tid; i < cnt; i += BLK) {
            int rec = tmp[S + i];
            int nl = rec & 511;
            int slot = (locRow[nl] - S) + atomicAdd(&fill[nl], 1);
            stage[slot] = rec >> 9;
        }
        __syncthreads();
        for (int i = tid; i < cnt; i += BLK) psrc[S + i] = stage[i];
    } else {
        // fallback (statistically unreachable): direct scatter within L2-hot window
        for (int i = tid; i < cnt; i += BLK) {
            int rec = tmp[S + i];
            int nl = rec & 511;
            int slot = locRow[nl] + atomicAdd(&fill[nl], 1);
            psrc[slot] = rec >> 9;
        }
    }
}

// out[n] = (-scale*dis[n]) * sum_{e in bucket(n)} dis[src]*v[src]  (- prev[n])
// thread t: node n = t/C, chunk c = t%C (4 floats). 4-wide gather unroll.
template <int F, bool HAVE_PREV>
__global__ void prop_csr_kernel(const int* __restrict__ rowptr, const int* __restrict__ psrc,
                                const float* __restrict__ dis, const float* __restrict__ v,
                                const float* __restrict__ prev, float* __restrict__ out,
                                float scale, int N) {
    constexpr int C = F / 4;
    int t = blockIdx.x * blockDim.x + threadIdx.x;
    int n = t / C;
    int c = t % C;
    if (n >= N) return;
    int beg = rowptr[n];
    int end = rowptr[n + 1];
    const float4* v4 = reinterpret_cast<const float4*>(v);
    float4 acc = make_float4(0.f, 0.f, 0.f, 0.f);
    int i = beg;
    for (; i + 3 < end; i += 4) {
        int s0 = psrc[i], s1 = psrc[i + 1], s2 = psrc[i + 2], s3 = psrc[i + 3];
        float w0 = dis[s0], w1 = dis[s1], w2 = dis[s2], w3 = dis[s3];
        float4 a0 = v4[(size_t)s0 * C + c];
        float4 a1 = v4[(size_t)s1 * C + c];
        float4 a2 = v4[(size_t)s2 * C + c];
        float4 a3 = v4[(size_t)s3 * C + c];
        acc.x += w0 * a0.x + w1 * a1.x + w2 * a2.x + w3 * a3.x;
        acc.y += w0 * a0.y + w1 * a1.y + w2 * a2.y + w3 * a3.y;
        acc.z += w0 * a0.z + w1 * a1.z + w2 * a2.z + w3 * a3.z;
        acc.w += w0 * a0.w + w1 * a1.w + w2 * a2.w + w3 * a3.w;
    }
    for (; i < end; i++) {
        int s0 = psrc[i];
        float w0 = dis[s0];
        float4 a0 = v4[(size_t)s0 * C + c];
        acc.x += w0 * a0.x; acc.y += w0 * a0.y; acc.z += w0 * a0.z; acc.w += w0 * a0.w;
    }
    float dn = -scale * dis[n];
    float4 r;
    if (HAVE_PREV) {
        float4 p = reinterpret_cast<const float4*>(prev)[(size_t)n * C + c];
        r = make_float4(dn * acc.x - p.x, dn * acc.y - p.y, dn * acc.z - p.z, dn * acc.w - p.w);
    } else {
        r = make_float4(dn * acc.x, dn * acc.y, dn * acc.z, dn * acc.w);
    }
    reinterpret_cast<float4*>(out)[(size_t)n * C + c] = r;
}

// h[n,j] = relu(b1[j] + sum_k sum_i Txk[n,i] * W1[k,i,j]); F_IN=32, HID=16, K=4
__global__ void combine1_kernel(const float* __restrict__ x, const float* __restrict__ t1,
                                const float* __restrict__ t2, const float* __restrict__ t3,
                                const float* __restrict__ W1, const float* __restrict__ b1,
                                float* __restrict__ h, int N) {
    __shared__ float sW[4 * 32 * 16];
    __shared__ float sb[16];
    for (int i = threadIdx.x; i < 4 * 32 * 16; i += blockDim.x) sW[i] = W1[i];
    if (threadIdx.x < 16) sb[threadIdx.x] = b1[threadIdx.x];
    __syncthreads();
    int n = blockIdx.x * blockDim.x + threadIdx.x;
    if (n >= N) return;
    float acc[16];
#pragma unroll
    for (int j = 0; j < 16; j++) acc[j] = sb[j];
    const float* rows[4] = {x + (size_t)n * 32, t1 + (size_t)n * 32,
                            t2 + (size_t)n * 32, t3 + (size_t)n * 32};
#pragma unroll
    for (int k = 0; k < 4; k++) {
        const float* row = rows[k];
        const float* Wk = sW + k * 512;
#pragma unroll
        for (int i = 0; i < 32; i++) {
            float xv = row[i];
#pragma unroll
            for (int j = 0; j < 16; j++) acc[j] += xv * Wk[i * 16 + j];
        }
    }
    float* ho = h + (size_t)n * 16;
#pragma unroll
    for (int j = 0; j < 16; j++) ho[j] = fmaxf(acc[j], 0.0f);
}

// o[n,c] = b2[c] + sum_k sum_i Sk[n,i]*W2[k,i,c]; then log_softmax. HID=16, C_OUT=10
__global__ void combine2_kernel(const float* __restrict__ h, const float* __restrict__ s1,
                                const float* __restrict__ s2, const float* __restrict__ s3,
                                const float* __restrict__ W2, const float* __restrict__ b2,
                                float* __restrict__ out, int N) {
    __shared__ float sW[4 * 16 * 10];
    __shared__ float sb[10];
    for (int i = threadIdx.x; i < 4 * 16 * 10; i += blockDim.x) sW[i] = W2[i];
    if (threadIdx.x < 10) sb[threadIdx.x] = b2[threadIdx.x];
    __syncthreads();
    int n = blockIdx.x * blockDim.x + threadIdx.x;
    if (n >= N) return;
    float acc[10];
#pragma unroll
    for (int c = 0; c < 10; c++) acc[c] = sb[c];
    const float* rows[4] = {h + (size_t)n * 16, s1 + (size_t)n * 16,
                            s2 + (size_t)n * 16, s3 + (size_t)n * 16};
#pragma unroll
    for (int k = 0; k < 4; k++) {
        const float* row = rows[k];
        const float* Wk = sW + k * 160;
#pragma unroll
        for (int i = 0; i < 16; i++) {
            float xv = row[i];
#pragma unroll
            for (int c = 0; c < 10; c++) acc[c] += xv * Wk[i * 10 + c];
        }
    }
    float m = acc[0];
#pragma unroll
    for (int c = 1; c < 10; c++) m = fmaxf(m, acc[c]);
    float sum = 0.0f;
#pragma unroll
    for (int c = 0; c < 10; c++) sum += expf(acc[c] - m);
    float lse = m + logf(sum);
    float* o = out + (size_t)n * 10;
#pragma unroll
    for (int c = 0; c < 10; c++) o[c] = acc[c] - lse;
}

extern "C" void kernel_launch(void* const* d_in, const int* in_sizes, int n_in,
                              void* d_out, int out_size, void* d_ws, size_t ws_size,
                              hipStream_t stream) {
    const float* x  = (const float*)d_in[0];
    const int*   ei = (const int*)d_in[1];
    const float* W1 = (const float*)d_in[2];
    const float* b1 = (const float*)d_in[3];
    const float* W2 = (const float*)d_in[4];
    const float* b2 = (const float*)d_in[5];
    float* out = (float*)d_out;

    const int N = in_sizes[0] / 32;   // 100000
    const int E = in_sizes[1] / 2;    // 1600000
    const int* src = ei;
    const int* dst = ei + E;

    const int NB    = (N + BLK - 1) / BLK;
    const int nbuck = (N + 511) / 512;        // 196

    // workspace layout (16B-aligned regions)
    char* w = (char*)d_ws;
    int*   deg    = (int*)w;              w += (size_t)N * 4;
    int*   rowptr = (int*)w;              w += (size_t)(N + 4) * 4;
    int*   bfill  = (int*)w;              w += 1024;
    int*   bsum   = (int*)w;              w += 1024 * 4;
    float* dis    = (float*)w;            w += (size_t)N * 4;
    int*   tmp    = (int*)w;              w += (size_t)E * 4;
    int*   psrc   = (int*)w;              w += (size_t)E * 4;
    float* txA    = (float*)w;            w += (size_t)32 * N * 4;
    float* txB    = (float*)w;            w += (size_t)32 * N * 4;
    float* txC    = (float*)w;            w += (size_t)32 * N * 4;
    float* hb     = (float*)w;            w += (size_t)16 * N * 4;
    float* s1 = txA;
    float* s2 = txA + (size_t)16 * N;
    float* s3 = txB;

    int gE4  = (E / 4 + BLK - 1) / BLK;
    int gN   = NB;
    int gP32 = (N * 8 + BLK - 1) / BLK;
    int gP16 = (N * 4 + BLK - 1) / BLK;
    int gCH  = (E + CHUNK - 1) / CHUNK;

    // ---- CSR build ----
    hipMemsetAsync(deg, 0, (size_t)N * sizeof(int), stream);
    hipMemsetAsync(bfill, 0, 1024, stream);
    hist_kernel<<<gE4, BLK, 0, stream>>>(dst, deg, E);
    dis_kernel<<<gN, BLK, 0, stream>>>(deg, dis, N);
    block_sums_kernel<<<NB, BLK, 0, stream>>>(deg, bsum, N);
    scan_partials_kernel<<<1, 512, 0, stream>>>(bsum, NB, rowptr, N, E);
    scan_final_kernel<<<NB, BLK, 0, stream>>>(deg, bsum, rowptr, N);
    binned_scatter_kernel<<<gCH, BLK, 0, stream>>>(src, dst, rowptr, bfill, tmp, E, N, nbuck);
    bucket_place_kernel<<<nbuck, BLK, 0, stream>>>(rowptr, tmp, psrc, N, nbuck);

    // ---- layer 1 (F=32) ----
    prop_csr_kernel<32, false><<<gP32, BLK, 0, stream>>>(rowptr, psrc, dis, x,   nullptr, txA, 1.0f, N);
    prop_csr_kernel<32, true ><<<gP32, BLK, 0, stream>>>(rowptr, psrc, dis, txA, x,       txB, 2.0f, N);
    prop_csr_kernel<32, true ><<<gP32, BLK, 0, stream>>>(rowptr, psrc, dis, txB, txA,     txC, 2.0f, N);
    combine1_kernel<<<gN, BLK, 0, stream>>>(x, txA, txB, txC, W1, b1, hb, N);

    // ---- layer 2 (F=16) ----
    prop_csr_kernel<16, false><<<gP16, BLK, 0, stream>>>(rowptr, psrc, dis, hb, nullptr, s1, 1.0f, N);
    prop_csr_kernel<16, true ><<<gP16, BLK, 0, stream>>>(rowptr, psrc, dis, s1, hb,      s2, 2.0f, N);
    prop_csr_kernel<16, true ><<<gP16, BLK, 0, stream>>>(rowptr, psrc, dis, s2, s1,      s3, 2.0f, N);
    combine2_kernel<<<gN, BLK, 0, stream>>>(hb, s1, s2, s3, W2, b2, out, N);
}

// Round 5
// 399.348 us; speedup vs baseline: 7.7764x; 1.1454x over previous
//
#include <hip/hip_runtime.h>
#include <hip/hip_bf16.h>
#include <math.h>

// ChebyNet: 2-layer ChebConv (K=4), N=100000, E=1600000, F 32->16->10, log_softmax.
//
// R5: R4's hist_kernel (1.6M random global atomics on deg) wrote 50 MB to HBM
// (device-scope atomic dirty-line writebacks) = 67 us. Degree/rowptr/dis are now
// derived inside the bucketed build -- no N-sized global atomics remain:
//   bucket_count: LDS-hist of 196 coarse buckets, 1 global atomic/(block,bucket)
//   bucket_scan:  scan 196 -> bbase
//   binned_scatter: LDS-group by bucket, flush coalesced into tmp (4B records)
//   bucket_place: per-bucket LDS degree count + scan -> rowptr/dis slices
//                 (coalesced), then LDS rank/stage -> psrc flush (coalesced)
// Edge record: (src<<9) | (dst&511). norm folded as out[n] = -dis[n]*sum dis[s]*v[s].

#define BLK 256
#define BLKP 512
#define NBUCK_MAX 256   // buckets = ceil(N/512); requires N <= 131072
#define CHUNK 8192      // edges per binned_scatter block
#define PLACE_CAP 10240 // staging capacity in bucket_place (avg bucket = 8192)

// LDS-privatized coarse-bucket histogram: bcnt[b] = #edges with dst>>9 == b
__global__ void bucket_count_kernel(const int* __restrict__ dst, int* __restrict__ bcnt,
                                    int E, int nbuck) {
    __shared__ int cnt[NBUCK_MAX];
    for (int b = threadIdx.x; b < NBUCK_MAX; b += BLK) cnt[b] = 0;
    __syncthreads();
    int t = blockIdx.x * BLK + threadIdx.x;
    int stride = gridDim.x * BLK;
    int E4 = E >> 2;
    for (int i = t; i < E4; i += stride) {
        int4 d = *reinterpret_cast<const int4*>(dst + i * 4);
        atomicAdd(&cnt[d.x >> 9], 1);
        atomicAdd(&cnt[d.y >> 9], 1);
        atomicAdd(&cnt[d.z >> 9], 1);
        atomicAdd(&cnt[d.w >> 9], 1);
    }
    if (t == 0) for (int j = E4 * 4; j < E; j++) atomicAdd(&bcnt[dst[j] >> 9], 1);
    __syncthreads();
    for (int b = threadIdx.x; b < nbuck; b += BLK)
        if (cnt[b]) atomicAdd(&bcnt[b], cnt[b]);
}

// single block: exclusive scan bcnt -> bbase; zero bfill; rowptr[N]=E, bbase[nbuck]=E
__global__ void bucket_scan_kernel(const int* __restrict__ bcnt, int* __restrict__ bbase,
                                   int* __restrict__ bfill, int* __restrict__ rowptr,
                                   int nbuck, int N, int E) {
    __shared__ int sh[NBUCK_MAX];
    int tid = threadIdx.x;
    int v = (tid < nbuck) ? bcnt[tid] : 0;
    sh[tid] = v;
    __syncthreads();
    for (int off = 1; off < BLK; off <<= 1) {
        int t = (tid >= off) ? sh[tid - off] : 0;
        __syncthreads();
        sh[tid] += t;
        __syncthreads();
    }
    if (tid < nbuck) bbase[tid] = sh[tid] - v;
    bfill[tid] = 0;
    if (tid == 0) { bbase[nbuck] = E; rowptr[N] = E; }
}

// Phase 1: group this block's CHUNK edges by bucket (dst>>9) in LDS, reserve
// global space per bucket, flush grouped runs coalesced into tmp.
__global__ void binned_scatter_kernel(const int* __restrict__ src, const int* __restrict__ dst,
                                      const int* __restrict__ bbase, int* __restrict__ bfill,
                                      int* __restrict__ tmp, int E, int nbuck) {
    __shared__ int cnt[NBUCK_MAX];
    __shared__ int lofs[NBUCK_MAX + 1];
    __shared__ int pos[NBUCK_MAX];
    __shared__ int gbase[NBUCK_MAX];
    __shared__ int stage[CHUNK];
    __shared__ unsigned char bkt[CHUNK];

    int tid = threadIdx.x;
    int e0 = blockIdx.x * CHUNK;
    int nE = min(CHUNK, E - e0);

    for (int b = tid; b < nbuck; b += BLK) { cnt[b] = 0; pos[b] = 0; }
    __syncthreads();

    for (int i = tid; i < nE; i += BLK) {
        int d = dst[e0 + i];
        atomicAdd(&cnt[d >> 9], 1);
    }
    __syncthreads();

    {
        int v = (tid < nbuck) ? cnt[tid] : 0;
        lofs[tid] = v;
        __syncthreads();
        for (int off = 1; off < BLK; off <<= 1) {
            int t = (tid >= off) ? lofs[tid - off] : 0;
            __syncthreads();
            lofs[tid] += t;
            __syncthreads();
        }
        int incl = lofs[tid];
        __syncthreads();
        lofs[tid] = incl - v;
        if (tid == 0) lofs[nbuck] = nE;
        if (tid < nbuck && v > 0)
            gbase[tid] = bbase[tid] + atomicAdd(&bfill[tid], v);
    }
    __syncthreads();

    for (int i = tid; i < nE; i += BLK) {
        int s = src[e0 + i];
        int d = dst[e0 + i];
        int b = d >> 9;
        int slot = lofs[b] + atomicAdd(&pos[b], 1);
        stage[slot] = (s << 9) | (d & 511);
        bkt[slot] = (unsigned char)b;
    }
    __syncthreads();

    for (int i = tid; i < nE; i += BLK) {
        int b = bkt[i];
        tmp[gbase[b] + (i - lofs[b])] = stage[i];
    }
}

// Phase 2: one block per bucket. LDS degree count -> scan -> rowptr/dis slices;
// then rank each record, stage final CSR order in LDS, flush coalesced.
__global__ void bucket_place_kernel(const int* __restrict__ bbase, const int* __restrict__ tmp,
                                    int* __restrict__ psrc, int* __restrict__ rowptr,
                                    float* __restrict__ dis, int N) {
    __shared__ int cnt[512];
    __shared__ int ofs[512];
    __shared__ int fill[512];
    __shared__ int stage[PLACE_CAP];

    int b = blockIdx.x;
    int tid = threadIdx.x;
    int n0 = b << 9;
    int nn = min(512, N - n0);
    int S = bbase[b];
    int tot = bbase[b + 1] - S;

    cnt[tid] = 0;
    fill[tid] = 0;
    __syncthreads();

    for (int i = tid; i < tot; i += BLKP) atomicAdd(&cnt[tmp[S + i] & 511], 1);
    __syncthreads();

    int v = cnt[tid];
    ofs[tid] = v;
    __syncthreads();
    for (int off = 1; off < 512; off <<= 1) {
        int t = (tid >= off) ? ofs[tid - off] : 0;
        __syncthreads();
        ofs[tid] += t;
        __syncthreads();
    }
    int excl = ofs[tid] - v;
    __syncthreads();
    ofs[tid] = excl;
    if (tid < nn) {
        rowptr[n0 + tid] = S + excl;
        dis[n0 + tid] = (v > 0) ? rsqrtf((float)v) : 0.0f;
    }
    __syncthreads();

    if (tot <= PLACE_CAP) {
        for (int i = tid; i < tot; i += BLKP) {
            int rec = tmp[S + i];
            int nl = rec & 511;
            int slot = ofs[nl] + atomicAdd(&fill[nl], 1);
            stage[slot] = rec >> 9;
        }
        __syncthreads();
        for (int i = tid; i < tot; i += BLKP) psrc[S + i] = stage[i];
    } else {
        // statistically unreachable fallback: direct scatter (L2-hot window)
        for (int i = tid; i < tot; i += BLKP) {
            int rec = tmp[S + i];
            int nl = rec & 511;
            int slot = S + ofs[nl] + atomicAdd(&fill[nl], 1);
            psrc[slot] = rec >> 9;
        }
    }
}

// out[n] = (-scale*dis[n]) * sum_{e in bucket(n)} dis[src]*v[src]  (- prev[n])
template <int F, bool HAVE_PREV>
__global__ void prop_csr_kernel(const int* __restrict__ rowptr, const int* __restrict__ psrc,
                                const float* __restrict__ dis, const float* __restrict__ v,
                                const float* __restrict__ prev, float* __restrict__ out,
                                float scale, int N) {
    constexpr int C = F / 4;
    int t = blockIdx.x * blockDim.x + threadIdx.x;
    int n = t / C;
    int c = t % C;
    if (n >= N) return;
    int beg = rowptr[n];
    int end = rowptr[n + 1];
    const float4* v4 = reinterpret_cast<const float4*>(v);
    float4 acc = make_float4(0.f, 0.f, 0.f, 0.f);
    int i = beg;
    for (; i + 3 < end; i += 4) {
        int s0 = psrc[i], s1 = psrc[i + 1], s2 = psrc[i + 2], s3 = psrc[i + 3];
        float w0 = dis[s0], w1 = dis[s1], w2 = dis[s2], w3 = dis[s3];
        float4 a0 = v4[(size_t)s0 * C + c];
        float4 a1 = v4[(size_t)s1 * C + c];
        float4 a2 = v4[(size_t)s2 * C + c];
        float4 a3 = v4[(size_t)s3 * C + c];
        acc.x += w0 * a0.x + w1 * a1.x + w2 * a2.x + w3 * a3.x;
        acc.y += w0 * a0.y + w1 * a1.y + w2 * a2.y + w3 * a3.y;
        acc.z += w0 * a0.z + w1 * a1.z + w2 * a2.z + w3 * a3.z;
        acc.w += w0 * a0.w + w1 * a1.w + w2 * a2.w + w3 * a3.w;
    }
    for (; i < end; i++) {
        int s0 = psrc[i];
        float w0 = dis[s0];
        float4 a0 = v4[(size_t)s0 * C + c];
        acc.x += w0 * a0.x; acc.y += w0 * a0.y; acc.z += w0 * a0.z; acc.w += w0 * a0.w;
    }
    float dn = -scale * dis[n];
    float4 r;
    if (HAVE_PREV) {
        float4 p = reinterpret_cast<const float4*>(prev)[(size_t)n * C + c];
        r = make_float4(dn * acc.x - p.x, dn * acc.y - p.y, dn * acc.z - p.z, dn * acc.w - p.w);
    } else {
        r = make_float4(dn * acc.x, dn * acc.y, dn * acc.z, dn * acc.w);
    }
    reinterpret_cast<float4*>(out)[(size_t)n * C + c] = r;
}

// h[n,j] = relu(b1[j] + sum_k sum_i Txk[n,i] * W1[k,i,j]); F_IN=32, HID=16, K=4
__global__ void combine1_kernel(const float* __restrict__ x, const float* __restrict__ t1,
                                const float* __restrict__ t2, const float* __restrict__ t3,
                                const float* __restrict__ W1, const float* __restrict__ b1,
                                float* __restrict__ h, int N) {
    __shared__ float sW[4 * 32 * 16];
    __shared__ float sb[16];
    for (int i = threadIdx.x; i < 4 * 32 * 16; i += blockDim.x) sW[i] = W1[i];
    if (threadIdx.x < 16) sb[threadIdx.x] = b1[threadIdx.x];
    __syncthreads();
    int n = blockIdx.x * blockDim.x + threadIdx.x;
    if (n >= N) return;
    float acc[16];
#pragma unroll
    for (int j = 0; j < 16; j++) acc[j] = sb[j];
    const float* rows[4] = {x + (size_t)n * 32, t1 + (size_t)n * 32,
                            t2 + (size_t)n * 32, t3 + (size_t)n * 32};
#pragma unroll
    for (int k = 0; k < 4; k++) {
        const float* row = rows[k];
        const float* Wk = sW + k * 512;
#pragma unroll
        for (int i = 0; i < 32; i++) {
            float xv = row[i];
#pragma unroll
            for (int j = 0; j < 16; j++) acc[j] += xv * Wk[i * 16 + j];
        }
    }
    float* ho = h + (size_t)n * 16;
#pragma unroll
    for (int j = 0; j < 16; j++) ho[j] = fmaxf(acc[j], 0.0f);
}

// o[n,c] = b2[c] + sum_k sum_i Sk[n,i]*W2[k,i,c]; then log_softmax. HID=16, C_OUT=10
__global__ void combine2_kernel(const float* __restrict__ h, const float* __restrict__ s1,
                                const float* __restrict__ s2, const float* __restrict__ s3,
                                const float* __restrict__ W2, const float* __restrict__ b2,
                                float* __restrict__ out, int N) {
    __shared__ float sW[4 * 16 * 10];
    __shared__ float sb[10];
    for (int i = threadIdx.x; i < 4 * 16 * 10; i += blockDim.x) sW[i] = W2[i];
    if (threadIdx.x < 10) sb[threadIdx.x] = b2[threadIdx.x];
    __syncthreads();
    int n = blockIdx.x * blockDim.x + threadIdx.x;
    if (n >= N) return;
    float acc[10];
#pragma unroll
    for (int c = 0; c < 10; c++) acc[c] = sb[c];
    const float* rows[4] = {h + (size_t)n * 16, s1 + (size_t)n * 16,
                            s2 + (size_t)n * 16, s3 + (size_t)n * 16};
#pragma unroll
    for (int k = 0; k < 4; k++) {
        const float* row = rows[k];
        const float* Wk = sW + k * 160;
#pragma unroll
        for (int i = 0; i < 16; i++) {
            float xv = row[i];
#pragma unroll
            for (int c = 0; c < 10; c++) acc[c] += xv * Wk[i * 10 + c];
        }
    }
    float m = acc[0];
#pragma unroll
    for (int c = 1; c < 10; c++) m = fmaxf(m, acc[c]);
    float sum = 0.0f;
#pragma unroll
    for (int c = 0; c < 10; c++) sum += expf(acc[c] - m);
    float lse = m + logf(sum);
    float* o = out + (size_t)n * 10;
#pragma unroll
    for (int c = 0; c < 10; c++) o[c] = acc[c] - lse;
}

extern "C" void kernel_launch(void* const* d_in, const int* in_sizes, int n_in,
                              void* d_out, int out_size, void* d_ws, size_t ws_size,
                              hipStream_t stream) {
    const float* x  = (const float*)d_in[0];
    const int*   ei = (const int*)d_in[1];
    const float* W1 = (const float*)d_in[2];
    const float* b1 = (const float*)d_in[3];
    const float* W2 = (const float*)d_in[4];
    const float* b2 = (const float*)d_in[5];
    float* out = (float*)d_out;

    const int N = in_sizes[0] / 32;   // 100000
    const int E = in_sizes[1] / 2;    // 1600000
    const int* src = ei;
    const int* dst = ei + E;

    const int nbuck = (N + 511) / 512;        // 196

    // workspace layout (16B-aligned regions)
    char* w = (char*)d_ws;
    int*   bcnt   = (int*)w;              w += NBUCK_MAX * 4;
    int*   bbase  = (int*)w;              w += (NBUCK_MAX + 4) * 4;
    int*   bfill  = (int*)w;              w += NBUCK_MAX * 4;
    int*   rowptr = (int*)w;              w += (size_t)(N + 4) * 4;
    float* dis    = (float*)w;            w += (size_t)N * 4;
    int*   tmp    = (int*)w;              w += (size_t)E * 4;
    int*   psrc   = (int*)w;              w += (size_t)E * 4;
    float* txA    = (float*)w;            w += (size_t)32 * N * 4;
    float* txB    = (float*)w;            w += (size_t)32 * N * 4;
    float* txC    = (float*)w;            w += (size_t)32 * N * 4;
    float* hb     = (float*)w;            w += (size_t)16 * N * 4;
    float* s1 = txA;
    float* s2 = txA + (size_t)16 * N;
    float* s3 = txB;

    int gN   = (N + BLK - 1) / BLK;
    int gP32 = (N * 8 + BLK - 1) / BLK;
    int gP16 = (N * 4 + BLK - 1) / BLK;
    int gCH  = (E + CHUNK - 1) / CHUNK;

    // ---- CSR build (no N-sized global atomics) ----
    hipMemsetAsync(bcnt, 0, NBUCK_MAX * sizeof(int), stream);
    bucket_count_kernel<<<1024, BLK, 0, stream>>>(dst, bcnt, E, nbuck);
    bucket_scan_kernel<<<1, BLK, 0, stream>>>(bcnt, bbase, bfill, rowptr, nbuck, N, E);
    binned_scatter_kernel<<<gCH, BLK, 0, stream>>>(src, dst, bbase, bfill, tmp, E, nbuck);
    bucket_place_kernel<<<nbuck, BLKP, 0, stream>>>(bbase, tmp, psrc, rowptr, dis, N);

    // ---- layer 1 (F=32) ----
    prop_csr_kernel<32, false><<<gP32, BLK, 0, stream>>>(rowptr, psrc, dis, x,   nullptr, txA, 1.0f, N);
    prop_csr_kernel<32, true ><<<gP32, BLK, 0, stream>>>(rowptr, psrc, dis, txA, x,       txB, 2.0f, N);
    prop_csr_kernel<32, true ><<<gP32, BLK, 0, stream>>>(rowptr, psrc, dis, txB, txA,     txC, 2.0f, N);
    combine1_kernel<<<gN, BLK, 0, stream>>>(x, txA, txB, txC, W1, b1, hb, N);

    // ---- layer 2 (F=16) ----
    prop_csr_kernel<16, false><<<gP16, BLK, 0, stream>>>(rowptr, psrc, dis, hb, nullptr, s1, 1.0f, N);
    prop_csr_kernel<16, true ><<<gP16, BLK, 0, stream>>>(rowptr, psrc, dis, s1, hb,      s2, 2.0f, N);
    prop_csr_kernel<16, true ><<<gP16, BLK, 0, stream>>>(rowptr, psrc, dis, s2, s1,      s3, 2.0f, N);
    combine2_kernel<<<gN, BLK, 0, stream>>>(hb, s1, s2, s3, W2, b2, out, N);
}

// Round 6
// 369.913 us; speedup vs baseline: 8.3952x; 1.0796x over previous
//
#include <hip/hip_runtime.h>
#include <hip/hip_bf16.h>
#include <math.h>

// ChebyNet: 2-layer ChebConv (K=4), N=100000, E=1600000, F 32->16->10, log_softmax.
//
// R6: F=32 props were gather-traffic-bound (FETCH 171MB ~= E x 128B fp32 row
// touches, R5). Layer-1 feature tables (x, Tx1..Tx3) now stored bf16: a
// 32-feat row = 64B = ONE cache line per edge (halves gather line touches).
// Accumulators / recurrence math / combines remain fp32; only storage is
// RNE-quantized. Layer 2 stays fp32 (16-feat fp32 row already = 64B = 1 line).
// CSR build (R5): bucket_count -> bucket_scan -> binned_scatter -> bucket_place,
// no N-sized global atomics. Edge record (src<<9)|(dst&511); norm folded as
// out[n] = -dis[n] * sum dis[s]*v[s].

#define BLK 256
#define BLKP 512
#define NBUCK_MAX 256   // buckets = ceil(N/512); requires N <= 131072
#define CHUNK 8192      // edges per binned_scatter block
#define PLACE_CAP 10240 // staging capacity in bucket_place (avg bucket = 8192)

// ---------- bf16 helpers (storage-only quantization) ----------
__device__ inline unsigned short f32_to_bf16_rne(float f) {
    unsigned int u = __float_as_uint(f);
    unsigned int rounding = 0x7FFFu + ((u >> 16) & 1u);
    return (unsigned short)((u + rounding) >> 16);
}
__device__ inline unsigned int pack_bf16x2(float a, float b) {
    return (unsigned int)f32_to_bf16_rne(a) | ((unsigned int)f32_to_bf16_rne(b) << 16);
}
// unpack uint = 2 bf16 -> 2 floats; low ushort is the even (lower-address) elem
__device__ inline void unpack8(const uint4 u, float* f) {
    const unsigned int* p = &u.x;
#pragma unroll
    for (int j = 0; j < 4; j++) {
        unsigned int w = p[j];
        f[2 * j]     = __uint_as_float(w << 16);
        f[2 * j + 1] = __uint_as_float(w & 0xFFFF0000u);
    }
}
__device__ inline void fma8(const uint4 u, float wgt, float* acc) {
    const unsigned int* p = &u.x;
#pragma unroll
    for (int j = 0; j < 4; j++) {
        unsigned int w = p[j];
        acc[2 * j]     += wgt * __uint_as_float(w << 16);
        acc[2 * j + 1] += wgt * __uint_as_float(w & 0xFFFF0000u);
    }
}

// fp32 [n8*8] -> bf16 rows packed as uint4 (8 elems / 16B)
__global__ void cvt_bf16_kernel(const float* __restrict__ in, uint4* __restrict__ out, int n8) {
    int t = blockIdx.x * blockDim.x + threadIdx.x;
    if (t >= n8) return;
    const float4* in4 = reinterpret_cast<const float4*>(in);
    float4 a = in4[t * 2], b = in4[t * 2 + 1];
    uint4 o;
    o.x = pack_bf16x2(a.x, a.y);
    o.y = pack_bf16x2(a.z, a.w);
    o.z = pack_bf16x2(b.x, b.y);
    o.w = pack_bf16x2(b.z, b.w);
    out[t] = o;
}

// ---------- CSR build (unchanged from R5) ----------
__global__ void bucket_count_kernel(const int* __restrict__ dst, int* __restrict__ bcnt,
                                    int E, int nbuck) {
    __shared__ int cnt[NBUCK_MAX];
    for (int b = threadIdx.x; b < NBUCK_MAX; b += BLK) cnt[b] = 0;
    __syncthreads();
    int t = blockIdx.x * BLK + threadIdx.x;
    int stride = gridDim.x * BLK;
    int E4 = E >> 2;
    for (int i = t; i < E4; i += stride) {
        int4 d = *reinterpret_cast<const int4*>(dst + i * 4);
        atomicAdd(&cnt[d.x >> 9], 1);
        atomicAdd(&cnt[d.y >> 9], 1);
        atomicAdd(&cnt[d.z >> 9], 1);
        atomicAdd(&cnt[d.w >> 9], 1);
    }
    if (t == 0) for (int j = E4 * 4; j < E; j++) atomicAdd(&bcnt[dst[j] >> 9], 1);
    __syncthreads();
    for (int b = threadIdx.x; b < nbuck; b += BLK)
        if (cnt[b]) atomicAdd(&bcnt[b], cnt[b]);
}

__global__ void bucket_scan_kernel(const int* __restrict__ bcnt, int* __restrict__ bbase,
                                   int* __restrict__ bfill, int* __restrict__ rowptr,
                                   int nbuck, int N, int E) {
    __shared__ int sh[NBUCK_MAX];
    int tid = threadIdx.x;
    int v = (tid < nbuck) ? bcnt[tid] : 0;
    sh[tid] = v;
    __syncthreads();
    for (int off = 1; off < BLK; off <<= 1) {
        int t = (tid >= off) ? sh[tid - off] : 0;
        __syncthreads();
        sh[tid] += t;
        __syncthreads();
    }
    if (tid < nbuck) bbase[tid] = sh[tid] - v;
    bfill[tid] = 0;
    if (tid == 0) { bbase[nbuck] = E; rowptr[N] = E; }
}

__global__ void binned_scatter_kernel(const int* __restrict__ src, const int* __restrict__ dst,
                                      const int* __restrict__ bbase, int* __restrict__ bfill,
                                      int* __restrict__ tmp, int E, int nbuck) {
    __shared__ int cnt[NBUCK_MAX];
    __shared__ int lofs[NBUCK_MAX + 1];
    __shared__ int pos[NBUCK_MAX];
    __shared__ int gbase[NBUCK_MAX];
    __shared__ int stage[CHUNK];
    __shared__ unsigned char bkt[CHUNK];

    int tid = threadIdx.x;
    int e0 = blockIdx.x * CHUNK;
    int nE = min(CHUNK, E - e0);

    for (int b = tid; b < nbuck; b += BLK) { cnt[b] = 0; pos[b] = 0; }
    __syncthreads();

    for (int i = tid; i < nE; i += BLK) {
        int d = dst[e0 + i];
        atomicAdd(&cnt[d >> 9], 1);
    }
    __syncthreads();

    {
        int v = (tid < nbuck) ? cnt[tid] : 0;
        lofs[tid] = v;
        __syncthreads();
        for (int off = 1; off < BLK; off <<= 1) {
            int t = (tid >= off) ? lofs[tid - off] : 0;
            __syncthreads();
            lofs[tid] += t;
            __syncthreads();
        }
        int incl = lofs[tid];
        __syncthreads();
        lofs[tid] = incl - v;
        if (tid == 0) lofs[nbuck] = nE;
        if (tid < nbuck && v > 0)
            gbase[tid] = bbase[tid] + atomicAdd(&bfill[tid], v);
    }
    __syncthreads();

    for (int i = tid; i < nE; i += BLK) {
        int s = src[e0 + i];
        int d = dst[e0 + i];
        int b = d >> 9;
        int slot = lofs[b] + atomicAdd(&pos[b], 1);
        stage[slot] = (s << 9) | (d & 511);
        bkt[slot] = (unsigned char)b;
    }
    __syncthreads();

    for (int i = tid; i < nE; i += BLK) {
        int b = bkt[i];
        tmp[gbase[b] + (i - lofs[b])] = stage[i];
    }
}

__global__ void bucket_place_kernel(const int* __restrict__ bbase, const int* __restrict__ tmp,
                                    int* __restrict__ psrc, int* __restrict__ rowptr,
                                    float* __restrict__ dis, int N) {
    __shared__ int cnt[512];
    __shared__ int ofs[512];
    __shared__ int fill[512];
    __shared__ int stage[PLACE_CAP];

    int b = blockIdx.x;
    int tid = threadIdx.x;
    int n0 = b << 9;
    int nn = min(512, N - n0);
    int S = bbase[b];
    int tot = bbase[b + 1] - S;

    cnt[tid] = 0;
    fill[tid] = 0;
    __syncthreads();

    for (int i = tid; i < tot; i += BLKP) atomicAdd(&cnt[tmp[S + i] & 511], 1);
    __syncthreads();

    int v = cnt[tid];
    ofs[tid] = v;
    __syncthreads();
    for (int off = 1; off < 512; off <<= 1) {
        int t = (tid >= off) ? ofs[tid - off] : 0;
        __syncthreads();
        ofs[tid] += t;
        __syncthreads();
    }
    int excl = ofs[tid] - v;
    __syncthreads();
    ofs[tid] = excl;
    if (tid < nn) {
        rowptr[n0 + tid] = S + excl;
        dis[n0 + tid] = (v > 0) ? rsqrtf((float)v) : 0.0f;
    }
    __syncthreads();

    if (tot <= PLACE_CAP) {
        for (int i = tid; i < tot; i += BLKP) {
            int rec = tmp[S + i];
            int nl = rec & 511;
            int slot = ofs[nl] + atomicAdd(&fill[nl], 1);
            stage[slot] = rec >> 9;
        }
        __syncthreads();
        for (int i = tid; i < tot; i += BLKP) psrc[S + i] = stage[i];
    } else {
        for (int i = tid; i < tot; i += BLKP) {
            int rec = tmp[S + i];
            int nl = rec & 511;
            int slot = S + ofs[nl] + atomicAdd(&fill[nl], 1);
            psrc[slot] = rec >> 9;
        }
    }
}

// ---------- layer-1 prop: bf16 tables, F=32 ----------
// rows = 32 bf16 = 64B = 4 x uint4 chunks; node n's lanes c=0..3 each own 8 feats.
// out[n] = (-scale*dis[n]) * sum dis[src]*v[src]  (- prev[n] if HAVE_PREV)
template <bool HAVE_PREV>
__global__ void prop_b16_kernel(const int* __restrict__ rowptr, const int* __restrict__ psrc,
                                const float* __restrict__ dis, const uint4* __restrict__ vb,
                                const uint4* __restrict__ prevb, uint4* __restrict__ outb,
                                float scale, int N) {
    int t = blockIdx.x * blockDim.x + threadIdx.x;
    int n = t >> 2;
    int c = t & 3;
    if (n >= N) return;
    int beg = rowptr[n];
    int end = rowptr[n + 1];
    float acc[8];
#pragma unroll
    for (int j = 0; j < 8; j++) acc[j] = 0.f;
    int i = beg;
    for (; i + 3 < end; i += 4) {
        int s0 = psrc[i], s1 = psrc[i + 1], s2 = psrc[i + 2], s3 = psrc[i + 3];
        uint4 a0 = vb[(size_t)s0 * 4 + c];
        uint4 a1 = vb[(size_t)s1 * 4 + c];
        uint4 a2 = vb[(size_t)s2 * 4 + c];
        uint4 a3 = vb[(size_t)s3 * 4 + c];
        float w0 = dis[s0], w1 = dis[s1], w2 = dis[s2], w3 = dis[s3];
        fma8(a0, w0, acc);
        fma8(a1, w1, acc);
        fma8(a2, w2, acc);
        fma8(a3, w3, acc);
    }
    for (; i < end; i++) {
        int s0 = psrc[i];
        uint4 a0 = vb[(size_t)s0 * 4 + c];
        fma8(a0, dis[s0], acc);
    }
    float dn = -scale * dis[n];
    float r[8];
    if (HAVE_PREV) {
        float p[8];
        unpack8(prevb[(size_t)n * 4 + c], p);
#pragma unroll
        for (int j = 0; j < 8; j++) r[j] = dn * acc[j] - p[j];
    } else {
#pragma unroll
        for (int j = 0; j < 8; j++) r[j] = dn * acc[j];
    }
    uint4 o;
    o.x = pack_bf16x2(r[0], r[1]);
    o.y = pack_bf16x2(r[2], r[3]);
    o.z = pack_bf16x2(r[4], r[5]);
    o.w = pack_bf16x2(r[6], r[7]);
    outb[(size_t)n * 4 + c] = o;
}

// ---------- layer-2 prop: fp32, F=16 (64B rows = already 1 line/edge) ----------
template <int F, bool HAVE_PREV>
__global__ void prop_csr_kernel(const int* __restrict__ rowptr, const int* __restrict__ psrc,
                                const float* __restrict__ dis, const float* __restrict__ v,
                                const float* __restrict__ prev, float* __restrict__ out,
                                float scale, int N) {
    constexpr int C = F / 4;
    int t = blockIdx.x * blockDim.x + threadIdx.x;
    int n = t / C;
    int c = t % C;
    if (n >= N) return;
    int beg = rowptr[n];
    int end = rowptr[n + 1];
    const float4* v4 = reinterpret_cast<const float4*>(v);
    float4 acc = make_float4(0.f, 0.f, 0.f, 0.f);
    int i = beg;
    for (; i + 3 < end; i += 4) {
        int s0 = psrc[i], s1 = psrc[i + 1], s2 = psrc[i + 2], s3 = psrc[i + 3];
        float w0 = dis[s0], w1 = dis[s1], w2 = dis[s2], w3 = dis[s3];
        float4 a0 = v4[(size_t)s0 * C + c];
        float4 a1 = v4[(size_t)s1 * C + c];
        float4 a2 = v4[(size_t)s2 * C + c];
        float4 a3 = v4[(size_t)s3 * C + c];
        acc.x += w0 * a0.x + w1 * a1.x + w2 * a2.x + w3 * a3.x;
        acc.y += w0 * a0.y + w1 * a1.y + w2 * a2.y + w3 * a3.y;
        acc.z += w0 * a0.z + w1 * a1.z + w2 * a2.z + w3 * a3.z;
        acc.w += w0 * a0.w + w1 * a1.w + w2 * a2.w + w3 * a3.w;
    }
    for (; i < end; i++) {
        int s0 = psrc[i];
        float w0 = dis[s0];
        float4 a0 = v4[(size_t)s0 * C + c];
        acc.x += w0 * a0.x; acc.y += w0 * a0.y; acc.z += w0 * a0.z; acc.w += w0 * a0.w;
    }
    float dn = -scale * dis[n];
    float4 r;
    if (HAVE_PREV) {
        float4 p = reinterpret_cast<const float4*>(prev)[(size_t)n * C + c];
        r = make_float4(dn * acc.x - p.x, dn * acc.y - p.y, dn * acc.z - p.z, dn * acc.w - p.w);
    } else {
        r = make_float4(dn * acc.x, dn * acc.y, dn * acc.z, dn * acc.w);
    }
    reinterpret_cast<float4*>(out)[(size_t)n * C + c] = r;
}

// h[n,j] = relu(b1[j] + x@W1[0] + sum_k Txk(bf16)@W1[k]); F_IN=32, HID=16
__global__ void combine1_kernel(const float* __restrict__ x, const uint4* __restrict__ t1b,
                                const uint4* __restrict__ t2b, const uint4* __restrict__ t3b,
                                const float* __restrict__ W1, const float* __restrict__ b1,
                                float* __restrict__ h, int N) {
    __shared__ float sW[4 * 32 * 16];
    __shared__ float sb[16];
    for (int i = threadIdx.x; i < 4 * 32 * 16; i += blockDim.x) sW[i] = W1[i];
    if (threadIdx.x < 16) sb[threadIdx.x] = b1[threadIdx.x];
    __syncthreads();
    int n = blockIdx.x * blockDim.x + threadIdx.x;
    if (n >= N) return;
    float acc[16];
#pragma unroll
    for (int j = 0; j < 16; j++) acc[j] = sb[j];
    // k = 0: fp32 x row
    {
        const float* row = x + (size_t)n * 32;
#pragma unroll
        for (int i = 0; i < 32; i++) {
            float xv = row[i];
#pragma unroll
            for (int j = 0; j < 16; j++) acc[j] += xv * sW[i * 16 + j];
        }
    }
    // k = 1..3: bf16 rows
    const uint4* tabs[3] = {t1b, t2b, t3b};
#pragma unroll
    for (int k = 0; k < 3; k++) {
        float row[32];
#pragma unroll
        for (int c = 0; c < 4; c++) unpack8(tabs[k][(size_t)n * 4 + c], row + c * 8);
        const float* Wk = sW + (k + 1) * 512;
#pragma unroll
        for (int i = 0; i < 32; i++) {
            float xv = row[i];
#pragma unroll
            for (int j = 0; j < 16; j++) acc[j] += xv * Wk[i * 16 + j];
        }
    }
    float* ho = h + (size_t)n * 16;
#pragma unroll
    for (int j = 0; j < 16; j++) ho[j] = fmaxf(acc[j], 0.0f);
}

// o[n,c] = b2[c] + sum_k Sk@W2[k]; then log_softmax. HID=16, C_OUT=10 (all fp32)
__global__ void combine2_kernel(const float* __restrict__ h, const float* __restrict__ s1,
                                const float* __restrict__ s2, const float* __restrict__ s3,
                                const float* __restrict__ W2, const float* __restrict__ b2,
                                float* __restrict__ out, int N) {
    __shared__ float sW[4 * 16 * 10];
    __shared__ float sb[10];
    for (int i = threadIdx.x; i < 4 * 16 * 10; i += blockDim.x) sW[i] = W2[i];
    if (threadIdx.x < 10) sb[threadIdx.x] = b2[threadIdx.x];
    __syncthreads();
    int n = blockIdx.x * blockDim.x + threadIdx.x;
    if (n >= N) return;
    float acc[10];
#pragma unroll
    for (int c = 0; c < 10; c++) acc[c] = sb[c];
    const float* rows[4] = {h + (size_t)n * 16, s1 + (size_t)n * 16,
                            s2 + (size_t)n * 16, s3 + (size_t)n * 16};
#pragma unroll
    for (int k = 0; k < 4; k++) {
        const float* row = rows[k];
        const float* Wk = sW + k * 160;
#pragma unroll
        for (int i = 0; i < 16; i++) {
            float xv = row[i];
#pragma unroll
            for (int c = 0; c < 10; c++) acc[c] += xv * Wk[i * 10 + c];
        }
    }
    float m = acc[0];
#pragma unroll
    for (int c = 1; c < 10; c++) m = fmaxf(m, acc[c]);
    float sum = 0.0f;
#pragma unroll
    for (int c = 0; c < 10; c++) sum += expf(acc[c] - m);
    float lse = m + logf(sum);
    float* o = out + (size_t)n * 10;
#pragma unroll
    for (int c = 0; c < 10; c++) o[c] = acc[c] - lse;
}

extern "C" void kernel_launch(void* const* d_in, const int* in_sizes, int n_in,
                              void* d_out, int out_size, void* d_ws, size_t ws_size,
                              hipStream_t stream) {
    const float* x  = (const float*)d_in[0];
    const int*   ei = (const int*)d_in[1];
    const float* W1 = (const float*)d_in[2];
    const float* b1 = (const float*)d_in[3];
    const float* W2 = (const float*)d_in[4];
    const float* b2 = (const float*)d_in[5];
    float* out = (float*)d_out;

    const int N = in_sizes[0] / 32;   // 100000
    const int E = in_sizes[1] / 2;    // 1600000
    const int* src = ei;
    const int* dst = ei + E;

    const int nbuck = (N + 511) / 512;        // 196

    // workspace layout (16B-aligned regions)
    char* w = (char*)d_ws;
    int*   bcnt   = (int*)w;              w += NBUCK_MAX * 4;
    int*   bbase  = (int*)w;              w += (NBUCK_MAX + 4) * 4;
    int*   bfill  = (int*)w;              w += NBUCK_MAX * 4;
    int*   rowptr = (int*)w;              w += (size_t)(N + 4) * 4;
    float* dis    = (float*)w;            w += (size_t)N * 4;
    int*   tmp    = (int*)w;              w += (size_t)E * 4;
    int*   psrc   = (int*)w;              w += (size_t)E * 4;
    uint4* x0b    = (uint4*)w;            w += (size_t)64 * N;   // 32 bf16/row
    uint4* t1b    = (uint4*)w;            w += (size_t)64 * N;
    uint4* t2b    = (uint4*)w;            w += (size_t)64 * N;
    uint4* t3b    = (uint4*)w;            w += (size_t)64 * N;
    float* hb     = (float*)w;            w += (size_t)16 * N * 4;
    float* s1     = (float*)w;            w += (size_t)16 * N * 4;
    float* s2     = (float*)w;            w += (size_t)16 * N * 4;
    float* s3     = (float*)w;            w += (size_t)16 * N * 4;

    int gN   = (N + BLK - 1) / BLK;
    int gB32 = (N * 4 + BLK - 1) / BLK;   // bf16 prop: 4 lanes/node
    int gP16 = (N * 4 + BLK - 1) / BLK;
    int gCVT = (N * 4 + BLK - 1) / BLK;   // 4N x 16B chunks
    int gCH  = (E + CHUNK - 1) / CHUNK;

    // ---- CSR build (no N-sized global atomics) ----
    hipMemsetAsync(bcnt, 0, NBUCK_MAX * sizeof(int), stream);
    bucket_count_kernel<<<1024, BLK, 0, stream>>>(dst, bcnt, E, nbuck);
    bucket_scan_kernel<<<1, BLK, 0, stream>>>(bcnt, bbase, bfill, rowptr, nbuck, N, E);
    binned_scatter_kernel<<<gCH, BLK, 0, stream>>>(src, dst, bbase, bfill, tmp, E, nbuck);
    bucket_place_kernel<<<nbuck, BLKP, 0, stream>>>(bbase, tmp, psrc, rowptr, dis, N);

    // ---- layer 1 (F=32, bf16 tables) ----
    cvt_bf16_kernel<<<gCVT, BLK, 0, stream>>>(x, x0b, N * 4);
    prop_b16_kernel<false><<<gB32, BLK, 0, stream>>>(rowptr, psrc, dis, x0b, nullptr, t1b, 1.0f, N); // Tx1
    prop_b16_kernel<true ><<<gB32, BLK, 0, stream>>>(rowptr, psrc, dis, t1b, x0b,     t2b, 2.0f, N); // Tx2
    prop_b16_kernel<true ><<<gB32, BLK, 0, stream>>>(rowptr, psrc, dis, t2b, t1b,     t3b, 2.0f, N); // Tx3
    combine1_kernel<<<gN, BLK, 0, stream>>>(x, t1b, t2b, t3b, W1, b1, hb, N);

    // ---- layer 2 (F=16, fp32) ----
    prop_csr_kernel<16, false><<<gP16, BLK, 0, stream>>>(rowptr, psrc, dis, hb, nullptr, s1, 1.0f, N);
    prop_csr_kernel<16, true ><<<gP16, BLK, 0, stream>>>(rowptr, psrc, dis, s1, hb,      s2, 2.0f, N);
    prop_csr_kernel<16, true ><<<gP16, BLK, 0, stream>>>(rowptr, psrc, dis, s2, s1,      s3, 2.0f, N);
    combine2_kernel<<<gN, BLK, 0, stream>>>(hb, s1, s2, s3, W2, b2, out, N);
}